// Round 1
// baseline (256.360 us; speedup 1.0000x reference)
//
#include <hip/hip_runtime.h>

#define NB 4
#define NH 16
#define NS 4096
#define ND 64
#define NBH (NB * NH)
#define EPSF 1e-6f

__device__ __forceinline__ float phi_f(float x) {
    // elu(x)+1 : x>0 ? x+1 : exp(x)
    return x > 0.0f ? x + 1.0f : __expf(x);
}

// ---------------- Pass 1: KV[bh] = phiK^T @ V  (64x64), K1[bh] = colsum(phiK) ----
#define P1_CHUNK 512
#define P1_SUB 64

__global__ __launch_bounds__(256)
void la_pass1(const float* __restrict__ Kin, const float* __restrict__ Vin,
              const float* __restrict__ Min, float* __restrict__ KV,
              float* __restrict__ K1)
{
    const int tid = threadIdx.x;
    const int bh  = blockIdx.y;
    const int bb  = bh >> 4;                 // H = 16
    const long long base = (long long)bh * NS * ND;
    const float* Kb = Kin + base;
    const float* Vb = Vin + base;
    const float* Mb = Min + (long long)bb * NS;

    __shared__ float sk[P1_SUB][ND];         // phi(K)*mask tile
    __shared__ float sv[P1_SUB][ND];         // V tile

    const int lrow = tid >> 4;               // 0..15 (loader row group)
    const int lcol = (tid & 15) * 4;         // 0..60 (loader col)
    const int d0 = (tid >> 4) * 4;           // this thread's 4 d-rows
    const int v0 = (tid & 15) * 4;           // this thread's 4 v-cols

    float acc[4][4];
    #pragma unroll
    for (int i = 0; i < 4; ++i)
        #pragma unroll
        for (int j = 0; j < 4; ++j) acc[i][j] = 0.0f;
    float acc1[4] = {0.f, 0.f, 0.f, 0.f};

    const int s0 = blockIdx.x * P1_CHUNK;
    const bool do_k1 = ((tid & 15) == 0);

    for (int t = 0; t < P1_CHUNK; t += P1_SUB) {
        __syncthreads();
        #pragma unroll
        for (int it = 0; it < 4; ++it) {
            const int r = lrow + 16 * it;
            const int srow = s0 + t + r;
            const float4 kq = *(const float4*)(Kb + (long long)srow * ND + lcol);
            const float4 vq = *(const float4*)(Vb + (long long)srow * ND + lcol);
            const float m = Mb[srow];
            float4 pk;
            pk.x = phi_f(kq.x) * m;
            pk.y = phi_f(kq.y) * m;
            pk.z = phi_f(kq.z) * m;
            pk.w = phi_f(kq.w) * m;
            *(float4*)(&sk[r][lcol]) = pk;
            *(float4*)(&sv[r][lcol]) = vq;
        }
        __syncthreads();
        #pragma unroll 4
        for (int r = 0; r < P1_SUB; ++r) {
            const float4 ka = *(const float4*)(&sk[r][d0]);
            const float4 vb = *(const float4*)(&sv[r][v0]);
            const float kav[4] = {ka.x, ka.y, ka.z, ka.w};
            const float vbv[4] = {vb.x, vb.y, vb.z, vb.w};
            #pragma unroll
            for (int i = 0; i < 4; ++i)
                #pragma unroll
                for (int j = 0; j < 4; ++j)
                    acc[i][j] += kav[i] * vbv[j];
            if (do_k1) {
                #pragma unroll
                for (int i = 0; i < 4; ++i) acc1[i] += kav[i];
            }
        }
    }

    float* kvb = KV + (long long)bh * ND * ND;
    #pragma unroll
    for (int i = 0; i < 4; ++i)
        #pragma unroll
        for (int j = 0; j < 4; ++j)
            atomicAdd(&kvb[(d0 + i) * ND + (v0 + j)], acc[i][j]);
    if (do_k1) {
        float* k1b = K1 + bh * ND;
        #pragma unroll
        for (int i = 0; i < 4; ++i) atomicAdd(&k1b[d0 + i], acc1[i]);
    }
}

// ---------------- Pass 2: out = (phiQ @ KV) / (phiQ @ k1 + eps) ----------------
#define P2_ROWS 128

__global__ __launch_bounds__(256)
void la_pass2(const float* __restrict__ Qin, const float* __restrict__ KV,
              const float* __restrict__ K1, float* __restrict__ Out)
{
    const int tid = threadIdx.x;
    const int bh  = blockIdx.y;
    const int s0  = blockIdx.x * P2_ROWS;
    const long long base = (long long)bh * NS * ND;

    __shared__ float sq[P2_ROWS][ND + 1];    // phi(q/8), +1 pad -> conflict-free
    __shared__ float skv[ND][ND];
    __shared__ float sk1[ND];
    __shared__ float snorm[P2_ROWS];

    // KV tile: 1024 float4, 4 per thread, coalesced
    {
        const float4* kvsrc = (const float4*)(KV + (long long)bh * ND * ND);
        float4* kvdst = (float4*)(&skv[0][0]);
        #pragma unroll
        for (int i = 0; i < 4; ++i) kvdst[tid + 256 * i] = kvsrc[tid + 256 * i];
        if (tid < 16) ((float4*)sk1)[tid] = ((const float4*)(K1 + bh * ND))[tid];
    }

    // Q tile: load, scale by 1/sqrt(64), phi, store padded
    {
        const int lrow = tid >> 4;
        const int lcol = (tid & 15) * 4;
        const float scale = 0.125f;
        #pragma unroll
        for (int it = 0; it < 8; ++it) {
            const int r = lrow + 16 * it;
            const float4 q4 = *(const float4*)(Qin + base + (long long)(s0 + r) * ND + lcol);
            sq[r][lcol + 0] = phi_f(q4.x * scale);
            sq[r][lcol + 1] = phi_f(q4.y * scale);
            sq[r][lcol + 2] = phi_f(q4.z * scale);
            sq[r][lcol + 3] = phi_f(q4.w * scale);
        }
    }
    __syncthreads();

    // normalizer per row
    if (tid < P2_ROWS) {
        float n = 0.0f;
        #pragma unroll 8
        for (int d = 0; d < ND; ++d) n += sq[tid][d] * sk1[d];
        snorm[tid] = n;
    }
    __syncthreads();

    // each thread: 4 rows x 8 cols of output
    const int sg = tid >> 3;                 // 0..31
    const int v0 = (tid & 7) * 8;            // 0..56
    const int r0 = sg * 4;

    float acc[4][8];
    #pragma unroll
    for (int j = 0; j < 4; ++j)
        #pragma unroll
        for (int k = 0; k < 8; ++k) acc[j][k] = 0.0f;

    #pragma unroll 4
    for (int d = 0; d < ND; ++d) {
        float q[4];
        #pragma unroll
        for (int j = 0; j < 4; ++j) q[j] = sq[r0 + j][d];
        const float4 b0 = *(const float4*)(&skv[d][v0]);
        const float4 b1 = *(const float4*)(&skv[d][v0 + 4]);
        const float bv[8] = {b0.x, b0.y, b0.z, b0.w, b1.x, b1.y, b1.z, b1.w};
        #pragma unroll
        for (int j = 0; j < 4; ++j)
            #pragma unroll
            for (int k = 0; k < 8; ++k)
                acc[j][k] += q[j] * bv[k];
    }

    float* outb = Out + base;
    #pragma unroll
    for (int j = 0; j < 4; ++j) {
        const int r = r0 + j;
        const float rn = 1.0f / (snorm[r] + EPSF);
        float4 o0, o1;
        o0.x = acc[j][0] * rn; o0.y = acc[j][1] * rn;
        o0.z = acc[j][2] * rn; o0.w = acc[j][3] * rn;
        o1.x = acc[j][4] * rn; o1.y = acc[j][5] * rn;
        o1.z = acc[j][6] * rn; o1.w = acc[j][7] * rn;
        *(float4*)(outb + (long long)(s0 + r) * ND + v0)     = o0;
        *(float4*)(outb + (long long)(s0 + r) * ND + v0 + 4) = o1;
    }
}

extern "C" void kernel_launch(void* const* d_in, const int* in_sizes, int n_in,
                              void* d_out, int out_size, void* d_ws, size_t ws_size,
                              hipStream_t stream)
{
    const float* Q = (const float*)d_in[0];
    const float* K = (const float*)d_in[1];
    const float* V = (const float*)d_in[2];
    const float* M = (const float*)d_in[3];
    float* Out = (float*)d_out;

    float* KV = (float*)d_ws;                          // [NBH][64][64]
    float* K1 = KV + (size_t)NBH * ND * ND;            // [NBH][64]

    const size_t zbytes = ((size_t)NBH * ND * ND + (size_t)NBH * ND) * sizeof(float);
    hipMemsetAsync(d_ws, 0, zbytes, stream);

    dim3 g1(NS / P1_CHUNK, NBH);                       // (8, 64)
    la_pass1<<<g1, dim3(256), 0, stream>>>(K, V, M, KV, K1);

    dim3 g2(NS / P2_ROWS, NBH);                        // (32, 64)
    la_pass2<<<g2, dim3(256), 0, stream>>>(Q, KV, K1, Out);
}